// Round 4
// baseline (389.952 us; speedup 1.0000x reference)
//
#include <hip/hip_runtime.h>
#include <math.h>

// FlowLevel: DIM=2, half=1 -> per-layer coupling depends on scalar v = z_b.
// t(v) and u(v) (pre-sigmoid) are piecewise-LINEAR in v (ReLU MLP).
// Tabulate (t, dt/dv, u, du/dv) per node; reconstruct with two tangent
// lines (exact for <=1 kink per cell). sigmoid/log-sigmoid computed exactly
// in the apply kernel from reconstructed u.
//
// Build kernel v3: block-cooperative, 64 nodes/block.
//  - k dimension split into two sequential halves of 64 -> 32 accumulators
//    per thread (a[4][4]+c[4][4]), epilogue folded per half, registers reused.
//  - __launch_bounds__(256,4): VGPR cap 128 == LDS-imposed 4 blocks/CU, so
//    the compiler keeps accumulators resident instead of strip-mining.
//  - sH rows stored permuted (prow = (node&3)*16 + node>>2) so one phase-2
//    ds_read_b128 hits 4 consecutive physical rows -> conflict-free.

constexpr int kDepth = 10;
constexpr int kWidth = 128;
constexpr float kVMin = -24.0f;
constexpr float kVMax =  24.0f;

__global__ __launch_bounds__(256, 4) void build_tables_kernel(
    const float* __restrict__ an_scale,
    const float* __restrict__ conv_w,
    const float* __restrict__ fc1_w, const float* __restrict__ fc1_b,
    const float* __restrict__ an1_scale, const float* __restrict__ an1_bias,
    const float* __restrict__ fc2_w, const float* __restrict__ fc2_b,
    const float* __restrict__ an2_scale, const float* __restrict__ an2_bias,
    const float* __restrict__ fc3_w, const float* __restrict__ fc3_b,
    const float* __restrict__ lsf,
    int tabN,
    float4* __restrict__ tab, float* __restrict__ extra)
{
  __shared__ float4 sW1s[32];          // w1/s1, as 32 float4 chunks
  __shared__ float4 sBb[32];           // (b1-z1)/s1
  __shared__ float  sH[64][132];       // h1 tile, PHYSICAL rows permuted
  __shared__ float  sB2z[128], sS2i[128], sW3a[128], sW3b[128];

  const int bpl   = tabN >> 6;                 // blocks per layer
  const int layer = blockIdx.x / bpl;
  const int node0 = (blockIdx.x % bpl) * 64;
  const int tid   = threadIdx.x;
  const float dv  = (kVMax - kVMin) / (float)(tabN - 1);

  // ---- phase 0: layer-uniform constants into LDS ----
  if (tid < 128) {
    const int j = tid;
    const float inv1 = 1.0f / an1_scale[layer*kWidth + j];
    ((float*)sW1s)[j] = fc1_w[layer*kWidth + j] * inv1;
    ((float*)sBb)[j]  = (fc1_b[layer*kWidth + j] - an1_bias[layer*kWidth + j]) * inv1;
    sB2z[j] = fc2_b[layer*kWidth + j] - an2_bias[layer*kWidth + j];
    sS2i[j] = 1.0f / an2_scale[layer*kWidth + j];
    sW3a[j] = fc3_w[layer*2*kWidth + j];
    sW3b[j] = fc3_w[layer*2*kWidth + kWidth + j];
  }
  __syncthreads();

  // ---- phase 1: fill h1 tile (64 nodes x 128 j), permuted rows ----
  {
    const int node = tid >> 2;            // logical node 0..63
    const int prow = (node & 3) * 16 + (node >> 2);
    const int cq0  = (tid & 3) * 8;       // float4 chunk base 0,8,16,24
    const float v = kVMin + dv * (float)(node0 + node);
#pragma unroll
    for (int c = 0; c < 8; ++c) {
      float4 w = sW1s[cq0 + c];
      float4 b = sBb[cq0 + c];
      float4 h;
      h.x = fmaxf(fmaf(v, w.x, b.x), 0.0f);
      h.y = fmaxf(fmaf(v, w.y, b.y), 0.0f);
      h.z = fmaxf(fmaf(v, w.z, b.z), 0.0f);
      h.w = fmaxf(fmaf(v, w.w, b.w), 0.0f);
      *(float4*)&sH[prow][(cq0 + c) * 4] = h;
    }
  }
  __syncthreads();

  // ---- phase 2: fused fc2 value+deriv dots, two k-halves ----
  const int kg = tid & 15;   // k-group
  const int ng = tid >> 4;   // node-group: logical node = ng*4 + nn

  float o0[4] = {0,0,0,0}, o1[4] = {0,0,0,0};
  float p0[4] = {0,0,0,0}, p1[4] = {0,0,0,0};

#pragma unroll
  for (int hh = 0; hh < 2; ++hh) {
    float a[4][4];   // [nn][kk] value dots
    float c[4][4];   // [nn][kk] deriv dots
#pragma unroll
    for (int nn = 0; nn < 4; ++nn)
#pragma unroll
      for (int kk = 0; kk < 4; ++kk) { a[nn][kk] = 0.0f; c[nn][kk] = 0.0f; }

    const float4* __restrict__ w2p =
        (const float4*)fc2_w + (size_t)layer * 4096 + (size_t)(hh * 64 + kg * 4) * 32;

    for (int jc = 0; jc < 32; ++jc) {
      float4 w0 = w2p[jc];            // k = base+0   (16-lane shared, L1-hot)
      float4 w1v = w2p[jc + 32];      // k = base+1
      float4 w2v = w2p[jc + 64];      // k = base+2
      float4 w3v = w2p[jc + 96];      // k = base+3
      float4 wg = sW1s[jc];           // broadcast
#pragma unroll
      for (int nn = 0; nn < 4; ++nn) {
        float4 h = *(const float4*)&sH[nn * 16 + ng][jc * 4];  // consecutive prows
        float dx = (h.x > 0.0f) ? wg.x : 0.0f;
        float dy = (h.y > 0.0f) ? wg.y : 0.0f;
        float dz = (h.z > 0.0f) ? wg.z : 0.0f;
        float dw = (h.w > 0.0f) ? wg.w : 0.0f;
        a[nn][0] = fmaf(h.w, w0.w, fmaf(h.z, w0.z, fmaf(h.y, w0.y, fmaf(h.x, w0.x, a[nn][0]))));
        a[nn][1] = fmaf(h.w, w1v.w, fmaf(h.z, w1v.z, fmaf(h.y, w1v.y, fmaf(h.x, w1v.x, a[nn][1]))));
        a[nn][2] = fmaf(h.w, w2v.w, fmaf(h.z, w2v.z, fmaf(h.y, w2v.y, fmaf(h.x, w2v.x, a[nn][2]))));
        a[nn][3] = fmaf(h.w, w3v.w, fmaf(h.z, w3v.z, fmaf(h.y, w3v.y, fmaf(h.x, w3v.x, a[nn][3]))));
        c[nn][0] = fmaf(dw, w0.w, fmaf(dz, w0.z, fmaf(dy, w0.y, fmaf(dx, w0.x, c[nn][0]))));
        c[nn][1] = fmaf(dw, w1v.w, fmaf(dz, w1v.z, fmaf(dy, w1v.y, fmaf(dx, w1v.x, c[nn][1]))));
        c[nn][2] = fmaf(dw, w2v.w, fmaf(dz, w2v.z, fmaf(dy, w2v.y, fmaf(dx, w2v.x, c[nn][2]))));
        c[nn][3] = fmaf(dw, w3v.w, fmaf(dz, w3v.z, fmaf(dy, w3v.y, fmaf(dx, w3v.x, c[nn][3]))));
      }
    }

    // epilogue for this k-half: relu + fc3 partials (reuses a/c registers)
#pragma unroll
    for (int kk = 0; kk < 4; ++kk) {
      const int k = hh * 64 + kg * 4 + kk;
      const float bz = sB2z[k], si = sS2i[k], wa = sW3a[k], wb = sW3b[k];
#pragma unroll
      for (int nn = 0; nn < 4; ++nn) {
        float pre  = (a[nn][kk] + bz) * si;
        float dpre = c[nn][kk] * si;
        bool  on   = pre > 0.0f;
        float h2   = on ? pre  : 0.0f;
        float dh2  = on ? dpre : 0.0f;
        o0[nn] = fmaf(h2,  wa, o0[nn]);
        p0[nn] = fmaf(dh2, wa, p0[nn]);
        o1[nn] = fmaf(h2,  wb, o1[nn]);
        p1[nn] = fmaf(dh2, wb, p1[nn]);
      }
    }
  }

  // ---- phase 3: reduce over kg lanes, write ----
#pragma unroll
  for (int off = 8; off >= 1; off >>= 1) {
#pragma unroll
    for (int nn = 0; nn < 4; ++nn) {
      o0[nn] += __shfl_xor(o0[nn], off);
      o1[nn] += __shfl_xor(o1[nn], off);
      p0[nn] += __shfl_xor(p0[nn], off);
      p1[nn] += __shfl_xor(p1[nn], off);
    }
  }
  if (kg == 0) {
    const float E0 = expf(lsf[layer*2 + 0]);
    const float E1 = expf(lsf[layer*2 + 1]);
    const float b30 = fc3_b[layer*2 + 0];
    const float b31 = fc3_b[layer*2 + 1];
#pragma unroll
    for (int nn = 0; nn < 4; ++nn) {
      const int q = node0 + ng*4 + nn;
      tab[(size_t)layer * tabN + q] =
          make_float4((o0[nn] + b30) * E0, p0[nn] * E0,
                      (o1[nn] + b31) * E1, p1[nn] * E1);
    }
  }

  // sample-independent logdet constant
  if (blockIdx.x == 0 && tid == 0) {
    float cst = 0.0f;
    for (int i = 0; i < kDepth; ++i) {
      cst -= logf(fabsf(an_scale[i*2+0]));
      cst -= logf(fabsf(an_scale[i*2+1]));
      const float* cw = conv_w + i * 4;
      float det = cw[0]*cw[3] - cw[1]*cw[2];
      cst += logf(fabsf(det));   // slogdet(conv)[1]
    }
    extra[0] = cst;
  }
}

// ---------------- main: per-sample 10-layer loop with two-line reconstruction ----------------
__global__ __launch_bounds__(256) void flow_apply_kernel(
    const float* __restrict__ x,
    const float* __restrict__ an_scale, const float* __restrict__ an_bias,
    const float* __restrict__ conv_w,
    const float4* __restrict__ tab, const float* __restrict__ extra,
    int tabN,
    float* __restrict__ out_z, float* __restrict__ out_ld, int n)
{
  int idx = blockIdx.x * blockDim.x + threadIdx.x;
  if (idx >= n) return;

  float2 z = reinterpret_cast<const float2*>(x)[idx];
  float ld = extra[0];
  const float dv = (kVMax - kVMin) / (float)(tabN - 1);
  const float inv_dv = (float)(tabN - 1) / (kVMax - kVMin);

#pragma unroll
  for (int i = 0; i < kDepth; ++i) {
    // actnorm
    float za = (z.x - an_bias[i*2+0]) / an_scale[i*2+0];
    float zb = (z.y - an_bias[i*2+1]) / an_scale[i*2+1];
    // 1x1 conv (2x2): z' = W z
    const float* cw = conv_w + i*4;
    float na = fmaf(cw[0], za, cw[1]*zb);
    float nb = fmaf(cw[2], za, cw[3]*zb);
    // table cell
    float xq = (nb - kVMin) * inv_dv;
    int qi = (int)floorf(xq);
    qi = qi < 0 ? 0 : (qi > tabN-2 ? tabN-2 : qi);
    float v0 = fmaf((float)qi, dv, kVMin);
    float v1 = v0 + dv;
    float4 e0 = tab[(size_t)i*tabN + qi];
    float4 e1 = tab[(size_t)i*tabN + qi + 1];
    // two-tangent-line reconstruction (exact for <=1 kink per cell)
    float tL = fmaf(nb - v0, e0.y, e0.x);
    float tR = fmaf(nb - v1, e1.y, e1.x);
    float tt = (e1.y >= e0.y) ? fmaxf(tL, tR) : fminf(tL, tR);
    float uL = fmaf(nb - v0, e0.w, e0.z);
    float uR = fmaf(nb - v1, e1.w, e1.z);
    float uu = (e1.w >= e0.w) ? fmaxf(uL, uR) : fminf(uL, uR);
    // exact sigmoid / log-sigmoid of arg = u + 2
    float arg = uu + 2.0f;
    float e = expf(-arg);
    float s = 1.0f / (1.0f + e);
    float lsv = -logf(1.0f + e);
    // coupling
    z.x = fmaf(s, na, tt);
    z.y = nb;
    ld += lsv;
  }

  reinterpret_cast<float2*>(out_z)[idx] = z;
  out_ld[idx] = ld;
}

extern "C" void kernel_launch(void* const* d_in, const int* in_sizes, int n_in,
                              void* d_out, int out_size, void* d_ws, size_t ws_size,
                              hipStream_t stream) {
  const float* x         = (const float*)d_in[0];
  const float* an_scale  = (const float*)d_in[1];
  const float* an_bias   = (const float*)d_in[2];
  const float* conv_w    = (const float*)d_in[3];
  const float* fc1_w     = (const float*)d_in[4];
  const float* fc1_b     = (const float*)d_in[5];
  const float* an1_scale = (const float*)d_in[6];
  const float* an1_bias  = (const float*)d_in[7];
  const float* fc2_w     = (const float*)d_in[8];
  const float* fc2_b     = (const float*)d_in[9];
  const float* an2_scale = (const float*)d_in[10];
  const float* an2_bias  = (const float*)d_in[11];
  const float* fc3_w     = (const float*)d_in[12];
  const float* fc3_b     = (const float*)d_in[13];
  const float* lsf       = (const float*)d_in[14];

  const int n = in_sizes[0] / 2;

  // workspace layout: [extra: 16 floats][table: float4 x kDepth x tabN]
  int tabN = 16384;
  while (tabN > 2048 &&
         (size_t)64 + (size_t)kDepth * tabN * sizeof(float4) > ws_size) {
    tabN >>= 1;
  }
  float* extra = (float*)d_ws;
  float4* tab  = (float4*)((char*)d_ws + 64);

  build_tables_kernel<<<kDepth * (tabN / 64), 256, 0, stream>>>(
      an_scale, conv_w, fc1_w, fc1_b, an1_scale, an1_bias,
      fc2_w, fc2_b, an2_scale, an2_bias, fc3_w, fc3_b, lsf, tabN, tab, extra);

  float* out_z  = (float*)d_out;
  float* out_ld = out_z + (size_t)2 * n;
  flow_apply_kernel<<<(n + 255) / 256, 256, 0, stream>>>(
      x, an_scale, an_bias, conv_w, tab, extra, tabN, out_z, out_ld, n);
}